// Round 2
// baseline (172.416 us; speedup 1.0000x reference)
//
#include <hip/hip_runtime.h>
#include <stdint.h>

#define D_IN  256
#define D_OUT 128
#define NSEQ  4096
#define NB    16
#define NBLK  512                       // 512 blocks x 128 rows = 65536 rows; no tail at 2 blocks/CU
#define LDS_BYTES 32768                 // bufA + bufB, 16 KB each

typedef __bf16 bf16x8 __attribute__((ext_vector_type(8)));
typedef float  f32x4  __attribute__((ext_vector_type(4)));

__device__ __forceinline__ unsigned short f2bf(float f) {
  __bf16 h = (__bf16)f;
  union { __bf16 h; unsigned short u; } c; c.h = h;
  return c.u;
}
__device__ __forceinline__ float bf2f(unsigned short u) {
  union { unsigned int u; float f; } a; a.u = ((unsigned int)u) << 16;
  return a.f;
}

// prep: Wa = Wp @ W1 (fp32 accum -> bf16, [n][k] layout), W2 transpose,
// be1 = bp @ W1 + b1. Folding Wp@W1 is exact math (ReLU is the only
// nonlinearity): relu((X@Wp+bp)@W1+b1) = relu(X@Wa + be1).
__global__ __launch_bounds__(256) void prep(
    const float* __restrict__ Wp, const float* __restrict__ W1, const float* __restrict__ W2,
    const float* __restrict__ bp, const float* __restrict__ b1,
    unsigned short* __restrict__ WaT, unsigned short* __restrict__ W2T, float* __restrict__ be1) {
  int b = blockIdx.x;
  if (b < 128) {
    __shared__ float wp[256];
    int k0 = b * 2;
    wp[threadIdx.x] = Wp[k0 * 128 + threadIdx.x];
    __syncthreads();
    int kk = threadIdx.x >> 7, n = threadIdx.x & 127;
    float s = 0.f;
#pragma unroll 16
    for (int j = 0; j < 128; ++j) s += wp[kk * 128 + j] * W1[j * 128 + n];
    WaT[n * 256 + (k0 + kk)] = f2bf(s);
  } else if (b < 192) {
    int t = (b - 128) * 256 + threadIdx.x;
    int k = t >> 7, n = t & 127;
    W2T[n * 128 + k] = f2bf(W2[t]);
  } else {
    if (threadIdx.x < 128) {
      int n = threadIdx.x;
      float s = b1[n];
#pragma unroll 16
      for (int j = 0; j < 128; ++j) s += bp[j] * W1[j * 128 + n];
      be1[n] = s;
    }
  }
}

// 512 blocks x 128 rows (two 64-row tiles per block, uniform 2 blocks/CU, no tail).
// Per tile: Y2 = relu(X@Wa + be1) (K=256, 2 chunks), Y3 = Y2@W2 + b2 (K=128).
// A tiles in swizzled LDS (bufA/bufB); B frags prefetched one GEMM ahead.
// Wave w: cols [w*32,w*32+32), all 64 rows. Per-block col sums over both
// tiles -> P[blk][128] (no atomics).
// LDS swizzle: (row,col) -> row*128 + ((col>>3 ^ (row&15))<<3) + (col&7).
template <bool USE_WS>
__global__ __launch_bounds__(256, 3) void fused2(
    const float* __restrict__ X,
    const unsigned short* __restrict__ WaT,
    const unsigned short* __restrict__ W2T,
    const float* __restrict__ be1, const float* __restrict__ b2v,
    unsigned short* __restrict__ Y3, float* __restrict__ out, float* __restrict__ P) {
  extern __shared__ unsigned short smem[];
  unsigned short* bufA = smem;            // 64x128 bf16 swizzled
  unsigned short* bufB = smem + 8192;

  const int tid  = threadIdx.x;
  const int lane = tid & 63;
  const int w    = tid >> 6;
  const int q    = lane >> 4;
  const int l16  = lane & 15;
  const int blk  = blockIdx.x;
  const int col0 = w * 32 + l16;
  const int col1 = col0 + 16;

  const float e0  = be1[col0], e1  = be1[col1];
  const float bb0 = b2v[col0], bb1 = b2v[col1];

  f32x4 acc[4][2];
  bf16x8 bA[4][2], bB[4][2];              // [ks][ct]
  float s0 = 0.f, s1 = 0.f;               // col sums carried across both tiles

#pragma unroll 1
  for (int t = 0; t < 2; ++t) {
    const int rowbase = blk * 128 + t * 64;

    // ---- prefetch Wa chunk0 B-frags ----
#pragma unroll
    for (int ks = 0; ks < 4; ++ks) {
      bA[ks][0] = *(const bf16x8*)(WaT + (size_t)col0 * 256 + ks * 32 + q * 8);
      bA[ks][1] = *(const bf16x8*)(WaT + (size_t)col1 * 256 + ks * 32 + q * 8);
    }

    // ---- stage X chunk0 -> bufA ----
#pragma unroll
    for (int it = 0; it < 8; ++it) {
      int i = tid + it * 256;
      int r = i >> 5, c4 = (i & 31) << 2;
      const float4 v = *(const float4*)(X + (size_t)(rowbase + r) * D_IN + c4);
      ushort4 u; u.x = f2bf(v.x); u.y = f2bf(v.y); u.z = f2bf(v.z); u.w = f2bf(v.w);
      *(ushort4*)(bufA + r * 128 + ((((c4 >> 3) ^ (r & 15)) << 3) + (c4 & 7))) = u;
    }

#pragma unroll
    for (int rt = 0; rt < 4; ++rt) {
      acc[rt][0] = (f32x4){0.f, 0.f, 0.f, 0.f};
      acc[rt][1] = (f32x4){0.f, 0.f, 0.f, 0.f};
    }
    __syncthreads();   // #1: bufA ready

    // ---- prefetch X chunk1 + Wa chunk1 frags (fly during GEMM-A c0) ----
    float4 xv[8];
#pragma unroll
    for (int it = 0; it < 8; ++it) {
      int i = tid + it * 256;
      int r = i >> 5, c4 = (i & 31) << 2;
      xv[it] = *(const float4*)(X + (size_t)(rowbase + r) * D_IN + 128 + c4);
    }
#pragma unroll
    for (int ks = 0; ks < 4; ++ks) {
      bB[ks][0] = *(const bf16x8*)(WaT + (size_t)col0 * 256 + 128 + ks * 32 + q * 8);
      bB[ks][1] = *(const bf16x8*)(WaT + (size_t)col1 * 256 + 128 + ks * 32 + q * 8);
    }

    // ---- GEMM-A chunk0 (bufA, bA) ----
#pragma unroll
    for (int ks = 0; ks < 4; ++ks)
#pragma unroll
      for (int rt = 0; rt < 4; ++rt) {
        bf16x8 a = *(const bf16x8*)(bufA + (rt * 16 + l16) * 128 + (((4 * ks + q) ^ l16) << 3));
        acc[rt][0] = __builtin_amdgcn_mfma_f32_16x16x32_bf16(a, bA[ks][0], acc[rt][0], 0, 0, 0);
        acc[rt][1] = __builtin_amdgcn_mfma_f32_16x16x32_bf16(a, bA[ks][1], acc[rt][1], 0, 0, 0);
      }

    // ---- stage X chunk1 -> bufB ----
#pragma unroll
    for (int it = 0; it < 8; ++it) {
      int i = tid + it * 256;
      int r = i >> 5, c4 = (i & 31) << 2;
      ushort4 u; u.x = f2bf(xv[it].x); u.y = f2bf(xv[it].y); u.z = f2bf(xv[it].z); u.w = f2bf(xv[it].w);
      *(ushort4*)(bufB + r * 128 + ((((c4 >> 3) ^ (r & 15)) << 3) + (c4 & 7))) = u;
    }
    __syncthreads();   // #2: bufB ready; all waves past GEMM-A c0 (bufA free)

    // ---- prefetch W2 frags into bA slots (Wa-c0 frags dead) ----
#pragma unroll
    for (int ks = 0; ks < 4; ++ks) {
      bA[ks][0] = *(const bf16x8*)(W2T + (size_t)col0 * 128 + ks * 32 + q * 8);
      bA[ks][1] = *(const bf16x8*)(W2T + (size_t)col1 * 128 + ks * 32 + q * 8);
    }

    // ---- GEMM-A chunk1 (bufB, bB) ----
#pragma unroll
    for (int ks = 0; ks < 4; ++ks)
#pragma unroll
      for (int rt = 0; rt < 4; ++rt) {
        bf16x8 a = *(const bf16x8*)(bufB + (rt * 16 + l16) * 128 + (((4 * ks + q) ^ l16) << 3));
        acc[rt][0] = __builtin_amdgcn_mfma_f32_16x16x32_bf16(a, bB[ks][0], acc[rt][0], 0, 0, 0);
        acc[rt][1] = __builtin_amdgcn_mfma_f32_16x16x32_bf16(a, bB[ks][1], acc[rt][1], 0, 0, 0);
      }

    // ---- epilogue A: Y2 = relu(acc + be1) -> bufA ----
#pragma unroll
    for (int rt = 0; rt < 4; ++rt)
#pragma unroll
      for (int r = 0; r < 4; ++r) {
        int row = rt * 16 + q * 4 + r;
        int sw = (row & 15) << 3;
        float v0 = acc[rt][0][r] + e0; v0 = v0 > 0.f ? v0 : 0.f;
        float v1 = acc[rt][1][r] + e1; v1 = v1 > 0.f ? v1 : 0.f;
        bufA[row * 128 + ((((col0 >> 3) << 3) ^ sw) + (col0 & 7))] = f2bf(v0);
        bufA[row * 128 + ((((col1 >> 3) << 3) ^ sw) + (col1 & 7))] = f2bf(v1);
      }
    __syncthreads();   // #3: Y2 visible; all waves past GEMM-A c1 (bufB free)

    // ---- GEMM-B (bufA, bA=W2 frags) ----
#pragma unroll
    for (int rt = 0; rt < 4; ++rt) {
      acc[rt][0] = (f32x4){0.f, 0.f, 0.f, 0.f};
      acc[rt][1] = (f32x4){0.f, 0.f, 0.f, 0.f};
    }
#pragma unroll
    for (int ks = 0; ks < 4; ++ks)
#pragma unroll
      for (int rt = 0; rt < 4; ++rt) {
        bf16x8 a = *(const bf16x8*)(bufA + (rt * 16 + l16) * 128 + (((4 * ks + q) ^ l16) << 3));
        acc[rt][0] = __builtin_amdgcn_mfma_f32_16x16x32_bf16(a, bA[ks][0], acc[rt][0], 0, 0, 0);
        acc[rt][1] = __builtin_amdgcn_mfma_f32_16x16x32_bf16(a, bA[ks][1], acc[rt][1], 0, 0, 0);
      }

    // ---- epilogue B: Y3 = acc + b2 -> bufB; accumulate col sums ----
#pragma unroll
    for (int rt = 0; rt < 4; ++rt)
#pragma unroll
      for (int r = 0; r < 4; ++r) {
        int row = rt * 16 + q * 4 + r;
        int sw = (row & 15) << 3;
        float v0 = acc[rt][0][r] + bb0;
        float v1 = acc[rt][1][r] + bb1;
        s0 += v0; s1 += v1;
        bufB[row * 128 + ((((col0 >> 3) << 3) ^ sw) + (col0 & 7))] = f2bf(v0);
        bufB[row * 128 + ((((col1 >> 3) << 3) ^ sw) + (col1 & 7))] = f2bf(v1);
      }
    __syncthreads();   // #4: Y3 in bufB complete

    // ---- copy-out tile ----
    if (USE_WS) {
#pragma unroll
      for (int it = 0; it < 4; ++it) {
        int i = tid + it * 256;
        int r = i >> 4, g = i & 15;
        *(uint4*)(Y3 + (size_t)(rowbase + r) * 128 + g * 8) =
            *(const uint4*)(bufB + r * 128 + ((g ^ (r & 15)) << 3));
      }
    } else {
#pragma unroll
      for (int it = 0; it < 8; ++it) {
        int i = tid + it * 256;
        int r = i >> 5, c4 = (i & 31) << 2;
        ushort4 u = *(const ushort4*)(bufB + r * 128 + ((((c4 >> 3) ^ (r & 15)) << 3) + (c4 & 7)));
        float4 v; v.x = bf2f(u.x); v.y = bf2f(u.y); v.z = bf2f(u.z); v.w = bf2f(u.w);
        *(float4*)(out + (size_t)(rowbase + r) * D_OUT + c4) = v;
      }
    }
    // next iteration stages into bufA only (copy-out above reads bufB; no
    // barrier needed between tiles beyond #1 of the next tile).
  }

  // ---- per-block col sums over 128 rows -> P[blk] ----
  s0 += __shfl_down(s0, 16); s0 += __shfl_down(s0, 32);
  s1 += __shfl_down(s1, 16); s1 += __shfl_down(s1, 32);
  if (lane < 16) {
    P[(size_t)blk * 128 + col0] = s0;
    P[(size_t)blk * 128 + col1] = s1;
  }
}

// finalize (ws path): each block (16 rows) redundantly computes S[batch] from
// its batch's 32 P-rows (L2-hot, 16 KB), then out[row][d] = S[b][d] - Y3[row][d].
__global__ __launch_bounds__(256) void finalize_ws(
    float* __restrict__ out, const unsigned short* __restrict__ Y3, const float* __restrict__ P) {
  __shared__ float S[128];
  const int tid  = threadIdx.x;
  const int row0 = blockIdx.x * 16;
  const int b    = row0 >> 12;
  if (tid < 128) {
    float s = 0.f;
    const float* p = P + (size_t)b * 32 * 128 + tid;
#pragma unroll
    for (int i = 0; i < 32; ++i) s += p[i * 128];
    S[tid] = s;
  }
  __syncthreads();
  size_t base = (size_t)row0 * 128 + (size_t)tid * 8;
  int col = (tid * 8) & 127;
  uint4 u = *(const uint4*)(Y3 + base);
  float4 s0 = *(const float4*)(S + col);
  float4 s1 = *(const float4*)(S + col + 4);
  union { unsigned int uu; float f; } t;
  float4 o0, o1;
  t.uu = u.x << 16;          o0.x = s0.x - t.f;
  t.uu = u.x & 0xFFFF0000u;  o0.y = s0.y - t.f;
  t.uu = u.y << 16;          o0.z = s0.z - t.f;
  t.uu = u.y & 0xFFFF0000u;  o0.w = s0.w - t.f;
  t.uu = u.z << 16;          o1.x = s1.x - t.f;
  t.uu = u.z & 0xFFFF0000u;  o1.y = s1.y - t.f;
  t.uu = u.w << 16;          o1.z = s1.z - t.f;
  t.uu = u.w & 0xFFFF0000u;  o1.w = s1.w - t.f;
  *(float4*)(out + base) = o0;
  *(float4*)(out + base + 4) = o1;
}

// fallback: out[row][d] = S[b][d] - out[row][d], in place (out holds Y3 f32)
__global__ __launch_bounds__(256) void finalize_ip(
    float* __restrict__ out, const float* __restrict__ P) {
  __shared__ float S[128];
  const int tid  = threadIdx.x;
  const int row0 = blockIdx.x * 16;
  const int b    = row0 >> 12;
  if (tid < 128) {
    float s = 0.f;
    const float* p = P + (size_t)b * 32 * 128 + tid;
#pragma unroll
    for (int i = 0; i < 32; ++i) s += p[i * 128];
    S[tid] = s;
  }
  __syncthreads();
  size_t base = (size_t)row0 * 128 + (size_t)tid * 8;
  int col = (tid * 8) & 127;
  float4 s0 = *(const float4*)(S + col);
  float4 s1 = *(const float4*)(S + col + 4);
  float4 y0 = *(const float4*)(out + base);
  float4 y1 = *(const float4*)(out + base + 4);
  float4 o0, o1;
  o0.x = s0.x - y0.x; o0.y = s0.y - y0.y; o0.z = s0.z - y0.z; o0.w = s0.w - y0.w;
  o1.x = s1.x - y1.x; o1.y = s1.y - y1.y; o1.z = s1.z - y1.z; o1.w = s1.w - y1.w;
  *(float4*)(out + base) = o0;
  *(float4*)(out + base + 4) = o1;
}

extern "C" void kernel_launch(void* const* d_in, const int* in_sizes, int n_in,
                              void* d_out, int out_size, void* d_ws, size_t ws_size,
                              hipStream_t stream) {
  const float* X  = (const float*)d_in[0];
  const float* Wp = (const float*)d_in[1];
  const float* bp = (const float*)d_in[2];
  const float* W1 = (const float*)d_in[3];
  const float* b1 = (const float*)d_in[4];
  const float* W2 = (const float*)d_in[5];
  const float* b2 = (const float*)d_in[6];
  float* out = (float*)d_out;

  char* ws = (char*)d_ws;
  float* be1          = (float*)ws;                               // 4 KB (512 B used)
  unsigned short* WaT = (unsigned short*)(ws + 4096);             // 64 KB (256x128 bf16 [n][k])
  unsigned short* W2T = (unsigned short*)(ws + 4096 + 65536);     // 32 KB
  float* P            = (float*)(ws + 4096 + 65536 + 32768);      // 256 KB (512 x 128)
  unsigned short* Y3  = (unsigned short*)(ws + 4096 + 65536 + 32768 + 262144);  // 16 MB

  const size_t need = 4096 + 65536 + 32768 + 262144 + (size_t)NB * NSEQ * D_OUT * 2;
  const bool use_ws = ws_size >= need;

  prep<<<193, 256, 0, stream>>>(Wp, W1, W2, bp, b1, WaT, W2T, be1);

  const int fin_blocks = (NB * NSEQ) / 16;  // 4096 blocks, 16 rows each
  if (use_ws) {
    fused2<true><<<NBLK, 256, LDS_BYTES, stream>>>(X, WaT, W2T, be1, b2, Y3, out, P);
    finalize_ws<<<fin_blocks, 256, 0, stream>>>(out, Y3, P);
  } else {
    fused2<false><<<NBLK, 256, LDS_BYTES, stream>>>(X, WaT, W2T, be1, b2, Y3, out, P);
    finalize_ip<<<fin_blocks, 256, 0, stream>>>(out, P);
  }
}

// Round 3
// 134.589 us; speedup vs baseline: 1.2811x; 1.2811x over previous
//
#include <hip/hip_runtime.h>
#include <hip/hip_cooperative_groups.h>
#include <stdint.h>

namespace cg = cooperative_groups;

#define D_IN  256
#define D_OUT 128
#define NSEQ  4096
#define NB    16
#define NBLK  1024                      // 64-row tiles; 4 blocks/CU -> all co-resident
#define LDS_BYTES 32768                 // bufA + bufB, 16 KB each

typedef __bf16 bf16x8 __attribute__((ext_vector_type(8)));
typedef float  f32x4  __attribute__((ext_vector_type(4)));

__device__ __forceinline__ unsigned short f2bf(float f) {
  __bf16 h = (__bf16)f;
  union { __bf16 h; unsigned short u; } c; c.h = h;
  return c.u;
}
__device__ __forceinline__ float bf2f(unsigned short u) {
  union { unsigned int u; float f; } a; a.u = ((unsigned int)u) << 16;
  return a.f;
}

// prep: Wa = Wp @ W1 (fp32 accum -> bf16, [n][k] layout), W2 transpose,
// be1 = bp @ W1 + b1. Folding Wp@W1 is exact math (ReLU is the only
// nonlinearity): relu((X@Wp+bp)@W1+b1) = relu(X@Wa + be1).
__global__ __launch_bounds__(256) void prep(
    const float* __restrict__ Wp, const float* __restrict__ W1, const float* __restrict__ W2,
    const float* __restrict__ bp, const float* __restrict__ b1,
    unsigned short* __restrict__ WaT, unsigned short* __restrict__ W2T, float* __restrict__ be1) {
  int b = blockIdx.x;
  if (b < 128) {
    __shared__ float wp[256];
    int k0 = b * 2;
    wp[threadIdx.x] = Wp[k0 * 128 + threadIdx.x];
    __syncthreads();
    int kk = threadIdx.x >> 7, n = threadIdx.x & 127;
    float s = 0.f;
#pragma unroll 16
    for (int j = 0; j < 128; ++j) s += wp[kk * 128 + j] * W1[j * 128 + n];
    WaT[n * 256 + (k0 + kk)] = f2bf(s);
  } else if (b < 192) {
    int t = (b - 128) * 256 + threadIdx.x;
    int k = t >> 7, n = t & 127;
    W2T[n * 128 + k] = f2bf(W2[t]);
  } else {
    if (threadIdx.x < 128) {
      int n = threadIdx.x;
      float s = b1[n];
#pragma unroll 16
      for (int j = 0; j < 128; ++j) s += bp[j] * W1[j * 128 + n];
      be1[n] = s;
    }
  }
}

// One 64-row tile: Y2 = relu(X@Wa + be1) (K=256, 2 chunks), Y3 = Y2@W2 + b2
// (K=128). Result: bufB holds Y3 (bf16, swizzled); s0/s1 hold per-wave col sums.
// Chunk-1 X loads issued BEFORE barrier #1 so both chunks' HBM latency drains
// under one barrier. LDS swizzle: (row,col) -> row*128 + ((col>>3 ^ (row&15))<<3) + (col&7).
__device__ __forceinline__ void tile_compute(
    const float* __restrict__ X,
    const unsigned short* __restrict__ WaT,
    const unsigned short* __restrict__ W2T,
    float e0, float e1, float bb0, float bb1,
    unsigned short* bufA, unsigned short* bufB,
    int rowbase, int tid, int q, int l16, int col0, int col1,
    float& s0, float& s1) {
  f32x4 acc[4][2];
  bf16x8 bA[4][2], bB[4][2];              // [ks][ct]

  // ---- prefetch Wa chunk0 B-frags ----
#pragma unroll
  for (int ks = 0; ks < 4; ++ks) {
    bA[ks][0] = *(const bf16x8*)(WaT + (size_t)col0 * 256 + ks * 32 + q * 8);
    bA[ks][1] = *(const bf16x8*)(WaT + (size_t)col1 * 256 + ks * 32 + q * 8);
  }

  // ---- stage X chunk0 -> bufA ----
#pragma unroll
  for (int it = 0; it < 8; ++it) {
    int i = tid + it * 256;
    int r = i >> 5, c4 = (i & 31) << 2;
    const float4 v = *(const float4*)(X + (size_t)(rowbase + r) * D_IN + c4);
    ushort4 u; u.x = f2bf(v.x); u.y = f2bf(v.y); u.z = f2bf(v.z); u.w = f2bf(v.w);
    *(ushort4*)(bufA + r * 128 + ((((c4 >> 3) ^ (r & 15)) << 3) + (c4 & 7))) = u;
  }

  // ---- issue X chunk1 loads NOW (drain under barrier #1 + GEMM-A c0) ----
  float4 xv[8];
#pragma unroll
  for (int it = 0; it < 8; ++it) {
    int i = tid + it * 256;
    int r = i >> 5, c4 = (i & 31) << 2;
    xv[it] = *(const float4*)(X + (size_t)(rowbase + r) * D_IN + 128 + c4);
  }

#pragma unroll
  for (int rt = 0; rt < 4; ++rt) {
    acc[rt][0] = (f32x4){0.f, 0.f, 0.f, 0.f};
    acc[rt][1] = (f32x4){0.f, 0.f, 0.f, 0.f};
  }
  __syncthreads();   // #1: bufA ready (xv also drained here)

  // ---- prefetch Wa chunk1 frags (L2-hot) ----
#pragma unroll
  for (int ks = 0; ks < 4; ++ks) {
    bB[ks][0] = *(const bf16x8*)(WaT + (size_t)col0 * 256 + 128 + ks * 32 + q * 8);
    bB[ks][1] = *(const bf16x8*)(WaT + (size_t)col1 * 256 + 128 + ks * 32 + q * 8);
  }

  // ---- GEMM-A chunk0 (bufA, bA) ----
#pragma unroll
  for (int ks = 0; ks < 4; ++ks)
#pragma unroll
    for (int rt = 0; rt < 4; ++rt) {
      bf16x8 a = *(const bf16x8*)(bufA + (rt * 16 + l16) * 128 + (((4 * ks + q) ^ l16) << 3));
      acc[rt][0] = __builtin_amdgcn_mfma_f32_16x16x32_bf16(a, bA[ks][0], acc[rt][0], 0, 0, 0);
      acc[rt][1] = __builtin_amdgcn_mfma_f32_16x16x32_bf16(a, bA[ks][1], acc[rt][1], 0, 0, 0);
    }

  // ---- stage X chunk1 -> bufB ----
#pragma unroll
  for (int it = 0; it < 8; ++it) {
    int i = tid + it * 256;
    int r = i >> 5, c4 = (i & 31) << 2;
    ushort4 u; u.x = f2bf(xv[it].x); u.y = f2bf(xv[it].y); u.z = f2bf(xv[it].z); u.w = f2bf(xv[it].w);
    *(ushort4*)(bufB + r * 128 + ((((c4 >> 3) ^ (r & 15)) << 3) + (c4 & 7))) = u;
  }
  __syncthreads();   // #2: bufB ready; all waves past GEMM-A c0 (bufA free)

  // ---- prefetch W2 frags into bA slots (Wa-c0 frags dead) ----
#pragma unroll
  for (int ks = 0; ks < 4; ++ks) {
    bA[ks][0] = *(const bf16x8*)(W2T + (size_t)col0 * 128 + ks * 32 + q * 8);
    bA[ks][1] = *(const bf16x8*)(W2T + (size_t)col1 * 128 + ks * 32 + q * 8);
  }

  // ---- GEMM-A chunk1 (bufB, bB) ----
#pragma unroll
  for (int ks = 0; ks < 4; ++ks)
#pragma unroll
    for (int rt = 0; rt < 4; ++rt) {
      bf16x8 a = *(const bf16x8*)(bufB + (rt * 16 + l16) * 128 + (((4 * ks + q) ^ l16) << 3));
      acc[rt][0] = __builtin_amdgcn_mfma_f32_16x16x32_bf16(a, bB[ks][0], acc[rt][0], 0, 0, 0);
      acc[rt][1] = __builtin_amdgcn_mfma_f32_16x16x32_bf16(a, bB[ks][1], acc[rt][1], 0, 0, 0);
    }

  // ---- epilogue A: Y2 = relu(acc + be1) -> bufA ----
#pragma unroll
  for (int rt = 0; rt < 4; ++rt)
#pragma unroll
    for (int r = 0; r < 4; ++r) {
      int row = rt * 16 + q * 4 + r;
      int sw = (row & 15) << 3;
      float v0 = acc[rt][0][r] + e0; v0 = v0 > 0.f ? v0 : 0.f;
      float v1 = acc[rt][1][r] + e1; v1 = v1 > 0.f ? v1 : 0.f;
      bufA[row * 128 + ((((col0 >> 3) << 3) ^ sw) + (col0 & 7))] = f2bf(v0);
      bufA[row * 128 + ((((col1 >> 3) << 3) ^ sw) + (col1 & 7))] = f2bf(v1);
    }
  __syncthreads();   // #3: Y2 visible; all waves past GEMM-A c1 (bufB free)

  // ---- GEMM-B (bufA, bA=W2 frags) ----
#pragma unroll
  for (int rt = 0; rt < 4; ++rt) {
    acc[rt][0] = (f32x4){0.f, 0.f, 0.f, 0.f};
    acc[rt][1] = (f32x4){0.f, 0.f, 0.f, 0.f};
  }
#pragma unroll
  for (int ks = 0; ks < 4; ++ks)
#pragma unroll
    for (int rt = 0; rt < 4; ++rt) {
      bf16x8 a = *(const bf16x8*)(bufA + (rt * 16 + l16) * 128 + (((4 * ks + q) ^ l16) << 3));
      acc[rt][0] = __builtin_amdgcn_mfma_f32_16x16x32_bf16(a, bA[ks][0], acc[rt][0], 0, 0, 0);
      acc[rt][1] = __builtin_amdgcn_mfma_f32_16x16x32_bf16(a, bA[ks][1], acc[rt][1], 0, 0, 0);
    }

  // ---- epilogue B: Y3 = acc + b2 -> bufB; accumulate col sums ----
#pragma unroll
  for (int rt = 0; rt < 4; ++rt)
#pragma unroll
    for (int r = 0; r < 4; ++r) {
      int row = rt * 16 + q * 4 + r;
      int sw = (row & 15) << 3;
      float v0 = acc[rt][0][r] + bb0;
      float v1 = acc[rt][1][r] + bb1;
      s0 += v0; s1 += v1;
      bufB[row * 128 + ((((col0 >> 3) << 3) ^ sw) + (col0 & 7))] = f2bf(v0);
      bufB[row * 128 + ((((col1 >> 3) << 3) ^ sw) + (col1 & 7))] = f2bf(v1);
    }
  __syncthreads();   // #4: Y3 in bufB complete
}

// Cooperative single-kernel path: tile -> P -> grid.sync -> S -> out = S - Y3(LDS).
// No Y3 global round-trip, no finalize launch. Requires all 1024 blocks
// co-resident (4/CU: 32 KB LDS x4 = 128 <= 160 KB, VGPR <= 128 via bounds).
__global__ __launch_bounds__(256, 4) void fused_coop(
    const float* __restrict__ X,
    const unsigned short* __restrict__ WaT,
    const unsigned short* __restrict__ W2T,
    const float* __restrict__ be1, const float* __restrict__ b2v,
    float* __restrict__ out, float* __restrict__ P) {
  extern __shared__ unsigned short smem[];
  unsigned short* bufA = smem;
  unsigned short* bufB = smem + 8192;

  const int tid  = threadIdx.x;
  const int lane = tid & 63;
  const int w    = tid >> 6;
  const int q    = lane >> 4;
  const int l16  = lane & 15;
  const int blk  = blockIdx.x;
  const int col0 = w * 32 + l16;
  const int col1 = col0 + 16;
  const int rowbase = blk * 64;

  const float e0  = be1[col0], e1  = be1[col1];
  const float bb0 = b2v[col0], bb1 = b2v[col1];

  float s0 = 0.f, s1 = 0.f;
  tile_compute(X, WaT, W2T, e0, e1, bb0, bb1, bufA, bufB,
               rowbase, tid, q, l16, col0, col1, s0, s1);

  // ---- per-block col sums -> P[blk] ----
  s0 += __shfl_down(s0, 16); s0 += __shfl_down(s0, 32);
  s1 += __shfl_down(s1, 16); s1 += __shfl_down(s1, 32);
  if (lane < 16) {
    P[(size_t)blk * 128 + col0] = s0;
    P[(size_t)blk * 128 + col1] = s1;
  }

  cg::this_grid().sync();   // all P visible device-wide; bufB (Y3) persists

  // ---- redundant per-block S reduce over this batch's 64 P-rows (L3-hot) ----
  const int kb  = (blk >> 6) << 6;     // first block of this batch
  const int col = tid & 127;
  const int h   = tid >> 7;
  float s = 0.f;
#pragma unroll
  for (int i = 0; i < 32; ++i)
    s += P[(size_t)(kb + h * 32 + i) * 128 + col];
  float* fs = (float*)bufA;            // bufA free (Y2 dead)
  fs[tid] = s;
  __syncthreads();
  if (tid < 128) fs[tid] += fs[tid + 128];
  __syncthreads();                     // fs[0..127] = S[batch]

  // ---- out = S - Y3 (from LDS) ----
#pragma unroll
  for (int it = 0; it < 8; ++it) {
    int i = tid + it * 256;
    int r = i >> 5, c4 = (i & 31) << 2;
    ushort4 u = *(const ushort4*)(bufB + r * 128 + ((((c4 >> 3) ^ (r & 15)) << 3) + (c4 & 7)));
    float4 sv = *(const float4*)(fs + c4);
    float4 o;
    o.x = sv.x - bf2f(u.x);
    o.y = sv.y - bf2f(u.y);
    o.z = sv.z - bf2f(u.z);
    o.w = sv.w - bf2f(u.w);
    *(float4*)(out + (size_t)(rowbase + r) * D_OUT + c4) = o;
  }
}

// Fallback main: tile -> copy-out Y3 (or f32 out) -> P. 1024 blocks, 4/CU.
template <bool USE_WS>
__global__ __launch_bounds__(256, 4) void fused2(
    const float* __restrict__ X,
    const unsigned short* __restrict__ WaT,
    const unsigned short* __restrict__ W2T,
    const float* __restrict__ be1, const float* __restrict__ b2v,
    unsigned short* __restrict__ Y3, float* __restrict__ out, float* __restrict__ P) {
  extern __shared__ unsigned short smem[];
  unsigned short* bufA = smem;
  unsigned short* bufB = smem + 8192;

  const int tid  = threadIdx.x;
  const int lane = tid & 63;
  const int w    = tid >> 6;
  const int q    = lane >> 4;
  const int l16  = lane & 15;
  const int blk  = blockIdx.x;
  const int col0 = w * 32 + l16;
  const int col1 = col0 + 16;
  const int rowbase = blk * 64;

  const float e0  = be1[col0], e1  = be1[col1];
  const float bb0 = b2v[col0], bb1 = b2v[col1];

  float s0 = 0.f, s1 = 0.f;
  tile_compute(X, WaT, W2T, e0, e1, bb0, bb1, bufA, bufB,
               rowbase, tid, q, l16, col0, col1, s0, s1);

  // ---- copy-out tile ----
  if (USE_WS) {
#pragma unroll
    for (int it = 0; it < 4; ++it) {
      int i = tid + it * 256;
      int r = i >> 4, g = i & 15;
      *(uint4*)(Y3 + (size_t)(rowbase + r) * 128 + g * 8) =
          *(const uint4*)(bufB + r * 128 + ((g ^ (r & 15)) << 3));
    }
  } else {
#pragma unroll
    for (int it = 0; it < 8; ++it) {
      int i = tid + it * 256;
      int r = i >> 5, c4 = (i & 31) << 2;
      ushort4 u = *(const ushort4*)(bufB + r * 128 + ((((c4 >> 3) ^ (r & 15)) << 3) + (c4 & 7)));
      float4 v; v.x = bf2f(u.x); v.y = bf2f(u.y); v.z = bf2f(u.z); v.w = bf2f(u.w);
      *(float4*)(out + (size_t)(rowbase + r) * D_OUT + c4) = v;
    }
  }

  // ---- per-block col sums -> P[blk] ----
  s0 += __shfl_down(s0, 16); s0 += __shfl_down(s0, 32);
  s1 += __shfl_down(s1, 16); s1 += __shfl_down(s1, 32);
  if (lane < 16) {
    P[(size_t)blk * 128 + col0] = s0;
    P[(size_t)blk * 128 + col1] = s1;
  }
}

// finalize (ws path): each block (16 rows) redundantly computes S[batch] from
// its batch's 64 P-rows (L2/L3-hot), then out[row][d] = S[b][d] - Y3[row][d].
__global__ __launch_bounds__(256) void finalize_ws(
    float* __restrict__ out, const unsigned short* __restrict__ Y3, const float* __restrict__ P) {
  __shared__ float S[128];
  const int tid  = threadIdx.x;
  const int row0 = blockIdx.x * 16;
  const int b    = row0 >> 12;
  {
    const int col = tid & 127;
    const int h   = tid >> 7;
    float s = 0.f;
    const float* p = P + (size_t)b * 64 * 128 + (size_t)h * 32 * 128 + col;
#pragma unroll
    for (int i = 0; i < 32; ++i) s += p[i * 128];
    if (h == 0) S[col] = s;
    __syncthreads();
    if (h == 1) S[col] += s;
    __syncthreads();
  }
  size_t base = (size_t)row0 * 128 + (size_t)tid * 8;
  int col = (tid * 8) & 127;
  uint4 u = *(const uint4*)(Y3 + base);
  float4 s0 = *(const float4*)(S + col);
  float4 s1 = *(const float4*)(S + col + 4);
  union { unsigned int uu; float f; } t;
  float4 o0, o1;
  t.uu = u.x << 16;          o0.x = s0.x - t.f;
  t.uu = u.x & 0xFFFF0000u;  o0.y = s0.y - t.f;
  t.uu = u.y << 16;          o0.z = s0.z - t.f;
  t.uu = u.y & 0xFFFF0000u;  o0.w = s0.w - t.f;
  t.uu = u.z << 16;          o1.x = s1.x - t.f;
  t.uu = u.z & 0xFFFF0000u;  o1.y = s1.y - t.f;
  t.uu = u.w << 16;          o1.z = s1.z - t.f;
  t.uu = u.w & 0xFFFF0000u;  o1.w = s1.w - t.f;
  *(float4*)(out + base) = o0;
  *(float4*)(out + base + 4) = o1;
}

// fallback finalize: out[row][d] = S[b][d] - out[row][d], in place
__global__ __launch_bounds__(256) void finalize_ip(
    float* __restrict__ out, const float* __restrict__ P) {
  __shared__ float S[128];
  const int tid  = threadIdx.x;
  const int row0 = blockIdx.x * 16;
  const int b    = row0 >> 12;
  {
    const int col = tid & 127;
    const int h   = tid >> 7;
    float s = 0.f;
    const float* p = P + (size_t)b * 64 * 128 + (size_t)h * 32 * 128 + col;
#pragma unroll
    for (int i = 0; i < 32; ++i) s += p[i * 128];
    if (h == 0) S[col] = s;
    __syncthreads();
    if (h == 1) S[col] += s;
    __syncthreads();
  }
  size_t base = (size_t)row0 * 128 + (size_t)tid * 8;
  int col = (tid * 8) & 127;
  float4 s0 = *(const float4*)(S + col);
  float4 s1 = *(const float4*)(S + col + 4);
  float4 y0 = *(const float4*)(out + base);
  float4 y1 = *(const float4*)(out + base + 4);
  float4 o0, o1;
  o0.x = s0.x - y0.x; o0.y = s0.y - y0.y; o0.z = s0.z - y0.z; o0.w = s0.w - y0.w;
  o1.x = s1.x - y1.x; o1.y = s1.y - y1.y; o1.z = s1.z - y1.z; o1.w = s1.w - y1.w;
  *(float4*)(out + base) = o0;
  *(float4*)(out + base + 4) = o1;
}

extern "C" void kernel_launch(void* const* d_in, const int* in_sizes, int n_in,
                              void* d_out, int out_size, void* d_ws, size_t ws_size,
                              hipStream_t stream) {
  const float* X  = (const float*)d_in[0];
  const float* Wp = (const float*)d_in[1];
  const float* bp = (const float*)d_in[2];
  const float* W1 = (const float*)d_in[3];
  const float* b1 = (const float*)d_in[4];
  const float* W2 = (const float*)d_in[5];
  const float* b2 = (const float*)d_in[6];
  float* out = (float*)d_out;

  char* ws = (char*)d_ws;
  float* be1          = (float*)ws;                               // 4 KB (512 B used)
  unsigned short* WaT = (unsigned short*)(ws + 4096);             // 64 KB (256x128 bf16 [n][k])
  unsigned short* W2T = (unsigned short*)(ws + 4096 + 65536);     // 32 KB
  float* P            = (float*)(ws + 4096 + 65536 + 32768);      // 512 KB (1024 x 128)
  unsigned short* Y3  = (unsigned short*)(ws + 4096 + 65536 + 32768 + 524288);  // 16 MB

  const size_t need = 4096 + 65536 + 32768 + 524288 + (size_t)NB * NSEQ * D_OUT * 2;
  const bool use_ws = ws_size >= need;

  prep<<<193, 256, 0, stream>>>(Wp, W1, W2, bp, b1, WaT, W2T, be1);

  // ---- cooperative attempt (checked; R1's failure mode was an unchecked
  // launch error -> silent zeros). Falls back to the 2-kernel path. ----
  static int coop_state = -1;           // -1 unknown, 1 good, 0 fallback
  bool launched = false;
  if (coop_state != 0 && ws_size >= 4096 + 65536 + 32768 + 524288) {
    int nb = 0;
    hipError_t e = hipOccupancyMaxActiveBlocksPerMultiprocessor(
        &nb, (const void*)fused_coop, 256, (size_t)LDS_BYTES);
    if (e == hipSuccess && nb >= 4) {   // 4 blocks/CU x 256 CU = 1024 co-resident
      void* args[7];
      args[0] = (void*)&X;
      args[1] = (void*)&WaT;
      args[2] = (void*)&W2T;
      args[3] = (void*)&be1;
      args[4] = (void*)&b2;
      args[5] = (void*)&out;
      args[6] = (void*)&P;
      e = hipLaunchCooperativeKernel((const void*)fused_coop, dim3(NBLK), dim3(256),
                                     args, (unsigned int)LDS_BYTES, stream);
      if (e == hipSuccess) { launched = true; coop_state = 1; }
    }
    if (!launched) coop_state = 0;
  }

  if (!launched) {
    const int fin_blocks = (NB * NSEQ) / 16;  // 4096 blocks, 16 rows each
    if (use_ws) {
      fused2<true><<<NBLK, 256, LDS_BYTES, stream>>>(X, WaT, W2T, be1, b2, Y3, out, P);
      finalize_ws<<<fin_blocks, 256, 0, stream>>>(out, Y3, P);
    } else {
      fused2<false><<<NBLK, 256, LDS_BYTES, stream>>>(X, WaT, W2T, be1, b2, Y3, out, P);
      finalize_ip<<<fin_blocks, 256, 0, stream>>>(out, P);
    }
  }
}

// Round 4
// 133.889 us; speedup vs baseline: 1.2878x; 1.0052x over previous
//
#include <hip/hip_runtime.h>
#include <stdint.h>

#define D_IN  256
#define D_OUT 128
#define NSEQ  4096
#define NB    16
#define NBLK  1024                      // 64-row tiles; 4 blocks/CU -> all 1024 co-resident
#define LDS_BYTES 32768                 // bufA + bufB, 16 KB each

typedef __bf16 bf16x8 __attribute__((ext_vector_type(8)));
typedef float  f32x4  __attribute__((ext_vector_type(4)));

__device__ __forceinline__ unsigned short f2bf(float f) {
  __bf16 h = (__bf16)f;
  union { __bf16 h; unsigned short u; } c; c.h = h;
  return c.u;
}
__device__ __forceinline__ float bf2f(unsigned short u) {
  union { unsigned int u; float f; } a; a.u = ((unsigned int)u) << 16;
  return a.f;
}

// prep: Wa = Wp @ W1 (fp32 accum -> bf16, [n][k] layout), W2 transpose,
// be1 = bp @ W1 + b1. Folding Wp@W1 is exact math (ReLU is the only
// nonlinearity): relu((X@Wp+bp)@W1+b1) = relu(X@Wa + be1).
__global__ __launch_bounds__(256) void prep(
    const float* __restrict__ Wp, const float* __restrict__ W1, const float* __restrict__ W2,
    const float* __restrict__ bp, const float* __restrict__ b1,
    unsigned short* __restrict__ WaT, unsigned short* __restrict__ W2T, float* __restrict__ be1) {
  int b = blockIdx.x;
  if (b < 128) {
    __shared__ float wp[256];
    int k0 = b * 2;
    wp[threadIdx.x] = Wp[k0 * 128 + threadIdx.x];
    __syncthreads();
    int kk = threadIdx.x >> 7, n = threadIdx.x & 127;
    float s = 0.f;
#pragma unroll 16
    for (int j = 0; j < 128; ++j) s += wp[kk * 128 + j] * W1[j * 128 + n];
    WaT[n * 256 + (k0 + kk)] = f2bf(s);
  } else if (b < 192) {
    int t = (b - 128) * 256 + threadIdx.x;
    int k = t >> 7, n = t & 127;
    W2T[n * 128 + k] = f2bf(W2[t]);
  } else {
    if (threadIdx.x < 128) {
      int n = threadIdx.x;
      float s = b1[n];
#pragma unroll 16
      for (int j = 0; j < 128; ++j) s += bp[j] * W1[j * 128 + n];
      be1[n] = s;
    }
  }
}

// Main: 1024 blocks x 64 rows, 4 blocks/CU (all co-resident, single round).
// Per tile: Y2 = relu(X@Wa + be1) (K=256, 2 chunks), Y3 = Y2@W2 + b2 (K=128).
// Chunk-1 X loads issued BEFORE barrier #1 so both chunks' HBM latency drains
// under one barrier + GEMM c0. A tiles in swizzled LDS; B frags prefetched one
// GEMM ahead. Wave w: cols [w*32,w*32+32). Per-block col sums -> P[blk][128].
// LDS swizzle: (row,col) -> row*128 + ((col>>3 ^ (row&15))<<3) + (col&7).
// NOTE (R3): cross-XCD grid.sync costs ~100+ us at this grid size; the split
// fused2+finalize structure is strictly cheaper than a cooperative fusion.
template <bool USE_WS>
__global__ __launch_bounds__(256, 4) void fused2(
    const float* __restrict__ X,
    const unsigned short* __restrict__ WaT,
    const unsigned short* __restrict__ W2T,
    const float* __restrict__ be1, const float* __restrict__ b2v,
    unsigned short* __restrict__ Y3, float* __restrict__ out, float* __restrict__ P) {
  extern __shared__ unsigned short smem[];
  unsigned short* bufA = smem;            // 64x128 bf16 swizzled
  unsigned short* bufB = smem + 8192;

  const int tid  = threadIdx.x;
  const int lane = tid & 63;
  const int w    = tid >> 6;
  const int q    = lane >> 4;
  const int l16  = lane & 15;
  const int blk  = blockIdx.x;
  const int col0 = w * 32 + l16;
  const int col1 = col0 + 16;
  const int rowbase = blk * 64;

  const float e0  = be1[col0], e1  = be1[col1];
  const float bb0 = b2v[col0], bb1 = b2v[col1];

  f32x4 acc[4][2];
  bf16x8 bA[4][2], bB[4][2];              // [ks][ct]

  // ---- prefetch Wa chunk0 B-frags ----
#pragma unroll
  for (int ks = 0; ks < 4; ++ks) {
    bA[ks][0] = *(const bf16x8*)(WaT + (size_t)col0 * 256 + ks * 32 + q * 8);
    bA[ks][1] = *(const bf16x8*)(WaT + (size_t)col1 * 256 + ks * 32 + q * 8);
  }

  // ---- stage X chunk0 -> bufA ----
#pragma unroll
  for (int it = 0; it < 8; ++it) {
    int i = tid + it * 256;
    int r = i >> 5, c4 = (i & 31) << 2;
    const float4 v = *(const float4*)(X + (size_t)(rowbase + r) * D_IN + c4);
    ushort4 u; u.x = f2bf(v.x); u.y = f2bf(v.y); u.z = f2bf(v.z); u.w = f2bf(v.w);
    *(ushort4*)(bufA + r * 128 + ((((c4 >> 3) ^ (r & 15)) << 3) + (c4 & 7))) = u;
  }

  // ---- issue X chunk1 loads NOW (drain under barrier #1 + GEMM-A c0) ----
  float4 xv[8];
#pragma unroll
  for (int it = 0; it < 8; ++it) {
    int i = tid + it * 256;
    int r = i >> 5, c4 = (i & 31) << 2;
    xv[it] = *(const float4*)(X + (size_t)(rowbase + r) * D_IN + 128 + c4);
  }

#pragma unroll
  for (int rt = 0; rt < 4; ++rt) {
    acc[rt][0] = (f32x4){0.f, 0.f, 0.f, 0.f};
    acc[rt][1] = (f32x4){0.f, 0.f, 0.f, 0.f};
  }
  __syncthreads();   // #1: bufA ready

  // ---- prefetch Wa chunk1 frags (L2-hot) ----
#pragma unroll
  for (int ks = 0; ks < 4; ++ks) {
    bB[ks][0] = *(const bf16x8*)(WaT + (size_t)col0 * 256 + 128 + ks * 32 + q * 8);
    bB[ks][1] = *(const bf16x8*)(WaT + (size_t)col1 * 256 + 128 + ks * 32 + q * 8);
  }

  // ---- GEMM-A chunk0 (bufA, bA) ----
#pragma unroll
  for (int ks = 0; ks < 4; ++ks)
#pragma unroll
    for (int rt = 0; rt < 4; ++rt) {
      bf16x8 a = *(const bf16x8*)(bufA + (rt * 16 + l16) * 128 + (((4 * ks + q) ^ l16) << 3));
      acc[rt][0] = __builtin_amdgcn_mfma_f32_16x16x32_bf16(a, bA[ks][0], acc[rt][0], 0, 0, 0);
      acc[rt][1] = __builtin_amdgcn_mfma_f32_16x16x32_bf16(a, bA[ks][1], acc[rt][1], 0, 0, 0);
    }

  // ---- stage X chunk1 -> bufB ----
#pragma unroll
  for (int it = 0; it < 8; ++it) {
    int i = tid + it * 256;
    int r = i >> 5, c4 = (i & 31) << 2;
    ushort4 u; u.x = f2bf(xv[it].x); u.y = f2bf(xv[it].y); u.z = f2bf(xv[it].z); u.w = f2bf(xv[it].w);
    *(ushort4*)(bufB + r * 128 + ((((c4 >> 3) ^ (r & 15)) << 3) + (c4 & 7))) = u;
  }
  __syncthreads();   // #2: bufB ready; all waves past GEMM-A c0 (bufA free)

  // ---- prefetch W2 frags into bA slots (Wa-c0 frags dead) ----
#pragma unroll
  for (int ks = 0; ks < 4; ++ks) {
    bA[ks][0] = *(const bf16x8*)(W2T + (size_t)col0 * 128 + ks * 32 + q * 8);
    bA[ks][1] = *(const bf16x8*)(W2T + (size_t)col1 * 128 + ks * 32 + q * 8);
  }

  // ---- GEMM-A chunk1 (bufB, bB) ----
#pragma unroll
  for (int ks = 0; ks < 4; ++ks)
#pragma unroll
    for (int rt = 0; rt < 4; ++rt) {
      bf16x8 a = *(const bf16x8*)(bufB + (rt * 16 + l16) * 128 + (((4 * ks + q) ^ l16) << 3));
      acc[rt][0] = __builtin_amdgcn_mfma_f32_16x16x32_bf16(a, bB[ks][0], acc[rt][0], 0, 0, 0);
      acc[rt][1] = __builtin_amdgcn_mfma_f32_16x16x32_bf16(a, bB[ks][1], acc[rt][1], 0, 0, 0);
    }

  // ---- epilogue A: Y2 = relu(acc + be1) -> bufA ----
#pragma unroll
  for (int rt = 0; rt < 4; ++rt)
#pragma unroll
    for (int r = 0; r < 4; ++r) {
      int row = rt * 16 + q * 4 + r;
      int sw = (row & 15) << 3;
      float v0 = acc[rt][0][r] + e0; v0 = v0 > 0.f ? v0 : 0.f;
      float v1 = acc[rt][1][r] + e1; v1 = v1 > 0.f ? v1 : 0.f;
      bufA[row * 128 + ((((col0 >> 3) << 3) ^ sw) + (col0 & 7))] = f2bf(v0);
      bufA[row * 128 + ((((col1 >> 3) << 3) ^ sw) + (col1 & 7))] = f2bf(v1);
    }
  __syncthreads();   // #3: Y2 visible; all waves past GEMM-A c1 (bufB free)

  // ---- GEMM-B (bufA, bA=W2 frags) ----
#pragma unroll
  for (int rt = 0; rt < 4; ++rt) {
    acc[rt][0] = (f32x4){0.f, 0.f, 0.f, 0.f};
    acc[rt][1] = (f32x4){0.f, 0.f, 0.f, 0.f};
  }
#pragma unroll
  for (int ks = 0; ks < 4; ++ks)
#pragma unroll
    for (int rt = 0; rt < 4; ++rt) {
      bf16x8 a = *(const bf16x8*)(bufA + (rt * 16 + l16) * 128 + (((4 * ks + q) ^ l16) << 3));
      acc[rt][0] = __builtin_amdgcn_mfma_f32_16x16x32_bf16(a, bA[ks][0], acc[rt][0], 0, 0, 0);
      acc[rt][1] = __builtin_amdgcn_mfma_f32_16x16x32_bf16(a, bA[ks][1], acc[rt][1], 0, 0, 0);
    }

  // ---- epilogue B: Y3 = acc + b2 -> bufB; accumulate col sums ----
  float s0 = 0.f, s1 = 0.f;
#pragma unroll
  for (int rt = 0; rt < 4; ++rt)
#pragma unroll
    for (int r = 0; r < 4; ++r) {
      int row = rt * 16 + q * 4 + r;
      int sw = (row & 15) << 3;
      float v0 = acc[rt][0][r] + bb0;
      float v1 = acc[rt][1][r] + bb1;
      s0 += v0; s1 += v1;
      bufB[row * 128 + ((((col0 >> 3) << 3) ^ sw) + (col0 & 7))] = f2bf(v0);
      bufB[row * 128 + ((((col1 >> 3) << 3) ^ sw) + (col1 & 7))] = f2bf(v1);
    }
  __syncthreads();   // #4: Y3 in bufB complete

  // ---- copy-out tile ----
  if (USE_WS) {
#pragma unroll
    for (int it = 0; it < 4; ++it) {
      int i = tid + it * 256;
      int r = i >> 4, g = i & 15;
      *(uint4*)(Y3 + (size_t)(rowbase + r) * 128 + g * 8) =
          *(const uint4*)(bufB + r * 128 + ((g ^ (r & 15)) << 3));
    }
  } else {
#pragma unroll
    for (int it = 0; it < 8; ++it) {
      int i = tid + it * 256;
      int r = i >> 5, c4 = (i & 31) << 2;
      ushort4 u = *(const ushort4*)(bufB + r * 128 + ((((c4 >> 3) ^ (r & 15)) << 3) + (c4 & 7)));
      float4 v; v.x = bf2f(u.x); v.y = bf2f(u.y); v.z = bf2f(u.z); v.w = bf2f(u.w);
      *(float4*)(out + (size_t)(rowbase + r) * D_OUT + c4) = v;
    }
  }

  // ---- per-block col sums -> P[blk] ----
  s0 += __shfl_down(s0, 16); s0 += __shfl_down(s0, 32);
  s1 += __shfl_down(s1, 16); s1 += __shfl_down(s1, 32);
  if (lane < 16) {
    P[(size_t)blk * 128 + col0] = s0;
    P[(size_t)blk * 128 + col1] = s1;
  }
}

// finalize (ws path): 1024 blocks x 64 rows. Each block redundantly computes
// S[batch] from its batch's 64 P-rows (32 KB, L2-hot), then
// out[row][d] = S[b][d] - Y3[row][d].
__global__ __launch_bounds__(256) void finalize_ws(
    float* __restrict__ out, const unsigned short* __restrict__ Y3, const float* __restrict__ P) {
  __shared__ float fs[256];
  const int tid  = threadIdx.x;
  const int row0 = blockIdx.x * 64;
  const int b    = row0 >> 12;
  {
    const int col = tid & 127;
    const int h   = tid >> 7;
    float s = 0.f;
    const float* p = P + (size_t)b * 64 * 128 + (size_t)h * 32 * 128 + col;
#pragma unroll
    for (int i = 0; i < 32; ++i) s += p[i * 128];
    fs[tid] = s;
  }
  __syncthreads();
  if (tid < 128) fs[tid] += fs[tid + 128];
  __syncthreads();                     // fs[0..127] = S[batch]

#pragma unroll
  for (int it = 0; it < 4; ++it) {
    int i = tid + it * 256;
    int r = i >> 4, g = (i & 15) * 8;
    size_t base = (size_t)(row0 + r) * 128 + g;
    uint4 u = *(const uint4*)(Y3 + base);
    float4 s0 = *(const float4*)(fs + g);
    float4 s1 = *(const float4*)(fs + g + 4);
    union { unsigned int uu; float f; } t;
    float4 o0, o1;
    t.uu = u.x << 16;          o0.x = s0.x - t.f;
    t.uu = u.x & 0xFFFF0000u;  o0.y = s0.y - t.f;
    t.uu = u.y << 16;          o0.z = s0.z - t.f;
    t.uu = u.y & 0xFFFF0000u;  o0.w = s0.w - t.f;
    t.uu = u.z << 16;          o1.x = s1.x - t.f;
    t.uu = u.z & 0xFFFF0000u;  o1.y = s1.y - t.f;
    t.uu = u.w << 16;          o1.z = s1.z - t.f;
    t.uu = u.w & 0xFFFF0000u;  o1.w = s1.w - t.f;
    *(float4*)(out + base) = o0;
    *(float4*)(out + base + 4) = o1;
  }
}

// fallback finalize: out[row][d] = S[b][d] - out[row][d], in place
__global__ __launch_bounds__(256) void finalize_ip(
    float* __restrict__ out, const float* __restrict__ P) {
  __shared__ float fs[256];
  const int tid  = threadIdx.x;
  const int row0 = blockIdx.x * 64;
  const int b    = row0 >> 12;
  {
    const int col = tid & 127;
    const int h   = tid >> 7;
    float s = 0.f;
    const float* p = P + (size_t)b * 64 * 128 + (size_t)h * 32 * 128 + col;
#pragma unroll
    for (int i = 0; i < 32; ++i) s += p[i * 128];
    fs[tid] = s;
  }
  __syncthreads();
  if (tid < 128) fs[tid] += fs[tid + 128];
  __syncthreads();

#pragma unroll
  for (int it = 0; it < 4; ++it) {
    int i = tid + it * 256;
    int r = i >> 4, g = (i & 15) * 8;
    size_t base = (size_t)(row0 + r) * 128 + g;
    float4 s0 = *(const float4*)(fs + g);
    float4 s1 = *(const float4*)(fs + g + 4);
    float4 y0 = *(const float4*)(out + base);
    float4 y1 = *(const float4*)(out + base + 4);
    float4 o0, o1;
    o0.x = s0.x - y0.x; o0.y = s0.y - y0.y; o0.z = s0.z - y0.z; o0.w = s0.w - y0.w;
    o1.x = s1.x - y1.x; o1.y = s1.y - y1.y; o1.z = s1.z - y1.z; o1.w = s1.w - y1.w;
    *(float4*)(out + base) = o0;
    *(float4*)(out + base + 4) = o1;
  }
}

extern "C" void kernel_launch(void* const* d_in, const int* in_sizes, int n_in,
                              void* d_out, int out_size, void* d_ws, size_t ws_size,
                              hipStream_t stream) {
  const float* X  = (const float*)d_in[0];
  const float* Wp = (const float*)d_in[1];
  const float* bp = (const float*)d_in[2];
  const float* W1 = (const float*)d_in[3];
  const float* b1 = (const float*)d_in[4];
  const float* W2 = (const float*)d_in[5];
  const float* b2 = (const float*)d_in[6];
  float* out = (float*)d_out;

  char* ws = (char*)d_ws;
  float* be1          = (float*)ws;                               // 4 KB (512 B used)
  unsigned short* WaT = (unsigned short*)(ws + 4096);             // 64 KB (256x128 bf16 [n][k])
  unsigned short* W2T = (unsigned short*)(ws + 4096 + 65536);     // 32 KB
  float* P            = (float*)(ws + 4096 + 65536 + 32768);      // 512 KB (1024 x 128)
  unsigned short* Y3  = (unsigned short*)(ws + 4096 + 65536 + 32768 + 524288);  // 16 MB

  const size_t need = 4096 + 65536 + 32768 + 524288 + (size_t)NB * NSEQ * D_OUT * 2;
  const bool use_ws = ws_size >= need;

  prep<<<193, 256, 0, stream>>>(Wp, W1, W2, bp, b1, WaT, W2T, be1);

  if (use_ws) {
    fused2<true><<<NBLK, 256, LDS_BYTES, stream>>>(X, WaT, W2T, be1, b2, Y3, out, P);
    finalize_ws<<<NBLK, 256, 0, stream>>>(out, Y3, P);
  } else {
    fused2<false><<<NBLK, 256, LDS_BYTES, stream>>>(X, WaT, W2T, be1, b2, Y3, out, P);
    finalize_ip<<<NBLK, 256, 0, stream>>>(out, P);
  }
}